// Round 13
// baseline (240.583 us; speedup 1.0000x reference)
//
#include <hip/hip_runtime.h>
#include <hip/hip_bf16.h>

// HeteroRGCN:
//   p_c = lrelu(mask(mean_t2c(x) @ W1[1] + b1[1])) @ (W2[0]@W_out) + b2[0]@W_out
//   p_d = same with W1[3], W2[2]
//   out[t] = b_out + mean_c2t(p_c) + mean_d2t(p_d)
// All random aggregation via LDS atomics + bucket sort (device atomics obey
// a ~48us/M random-line-op law). Fixed per-bucket capacities -> arithmetic
// bucket bases (no hist/prefix). gather and transform SPLIT (fusion drops
// random-fetch BW 3.7->2.1 TB/s, r12); means passed as bf16 to halve traffic.

#define NT 500000
#define NC 200000
#define ND 100000
#define NE 1000000
#define H  64
#define CAP_T2C 32      // per-node ELL cap, dst NC (lambda=5)
#define CAP_T2D 48      // per-node ELL cap, dst ND (lambda=10)

#define PACK_SCALE 65536.0f
#define PACK_BIAS  262144   // 4 * 65536
#define FIELD_MASK 0x3FFFFFFULL

// radix: rel 0 t2c (shift11, 98 bk), rel 1 t2d (shift10, 98 bk),
//        rel 2 c2t (shift11, 245 bk), rel 3 d2t (shift11, 245 bk)
#define NBK_MAX 245
#define OFF_C2T 196         // cur[] index offsets
#define OFF_D2T 441
#define EPB 4096
#define BPR 245             // ceil(NE/EPB)
#define CAP_BK1 11776       // bucket capacity, L1 (exp 10240, +15 sigma)
#define CAP_BK2 4864        // bucket capacity, L2 (exp 4096, +12 sigma)

#define CB512 7813          // compress blocks: ceil(4,000,000 / 512)

__device__ __forceinline__ void rel_params(int rel, int& shift, int& hoff, int& nbk) {
    shift = (rel == 1) ? 10 : 11;
    hoff = (rel == 0) ? 0 : (rel == 1) ? 98 : (rel == 2) ? OFF_C2T : OFF_D2T;
    nbk = (rel < 2) ? 98 : 245;
}

#define BFP(x) (u = __float_as_uint(x), (u + 0x7fffu + ((u >> 16) & 1u)) >> 16)

// ---- fused: radix scatter (implicit bases) + feature compress + prep_fold ----
__global__ __launch_bounds__(512)
void scatter_compress(const int* __restrict__ st2c, const int* __restrict__ dt2c,
                      const int* __restrict__ st2d, const int* __restrict__ dt2d,
                      const int* __restrict__ sc2t, const int* __restrict__ dc2t,
                      const int* __restrict__ sd2t, const int* __restrict__ dd2t,
                      int* __restrict__ cur,
                      unsigned long long* __restrict__ bedges1,
                      unsigned long long* __restrict__ bedges2,
                      const float* __restrict__ X, unsigned int* __restrict__ Xb,
                      const float* __restrict__ W2, const float* __restrict__ b2,
                      const float* __restrict__ Wout,
                      float* __restrict__ Wc, float* __restrict__ bc) {
    __shared__ unsigned long long le[EPB];
    __shared__ int h[NBK_MAX], pref[NBK_MAX], gbase[NBK_MAX], csr[NBK_MAX];
    __shared__ int sc[256];
    int t = threadIdx.x, b = blockIdx.x;

    if (b >= 4 * BPR) {
        int cb = b - 4 * BPR;
        if (cb < CB512) {
            size_t idx = (size_t)cb * 512 + t;
            if (idx < 4000000) {
                const float4 f0 = ((const float4*)X)[idx * 2];
                const float4 f1 = ((const float4*)X)[idx * 2 + 1];
                uint4 o;
                unsigned int u;
                o.x = BFP(f0.x) | (BFP(f0.y) << 16);
                o.y = BFP(f0.z) | (BFP(f0.w) << 16);
                o.z = BFP(f1.x) | (BFP(f1.y) << 16);
                o.w = BFP(f1.z) | (BFP(f1.w) << 16);
                ((uint4*)Xb)[idx] = o;
            }
        } else if (t < 256) {
            // prep_fold: Wc[rel][k][o] = sum_j W2[rel*2][k][j] * Wout[j][o]
            int rel = t >> 7;
            int rem = t & 127;
            int k = rem >> 1, o = rem & 1;
            const float* W2r = W2 + (rel ? 2 : 0) * H * H;
            float s = 0.0f;
            for (int j = 0; j < H; ++j) s += W2r[k * H + j] * Wout[j * 2 + o];
            Wc[rel * 128 + k * 2 + o] = s;
            if (rem < 4) {
                int r2 = rem >> 1, o2 = rem & 1;
                const float* b2r = b2 + (r2 ? 2 : 0) * H;
                float sb = 0.0f;
                for (int j = 0; j < H; ++j) sb += b2r[j] * Wout[j * 2 + o2];
                bc[r2 * 2 + o2] = sb;
            }
        }
        return;
    }

    int rel = b / BPR;
    int bb = b - rel * BPR;
    const int* sp = (rel == 0) ? st2c : (rel == 1) ? st2d : (rel == 2) ? sc2t : sd2t;
    const int* dp = (rel == 0) ? dt2c : (rel == 1) ? dt2d : (rel == 2) ? dc2t : dd2t;
    int shift, hoff, nbk;
    rel_params(rel, shift, hoff, nbk);
    unsigned long long* bedges = (rel < 2) ? bedges1 : bedges2;
    int bkoff = (rel == 1) ? 98 : (rel == 3) ? 245 : 0;
    int bkcap = (rel < 2) ? CAP_BK1 : CAP_BK2;

    for (int i = t; i < nbk; i += 512) { h[i] = 0; csr[i] = 0; }
    __syncthreads();

    int base = bb * EPB + t * 8;
    bool ok = base < NE;
    int4 d0, d1, s0, s1;
    if (ok) {
        d0 = *(const int4*)(dp + base);
        d1 = *(const int4*)(dp + base + 4);
        s0 = *(const int4*)(sp + base);
        s1 = *(const int4*)(sp + base + 4);
        atomicAdd(&h[d0.x >> shift], 1);
        atomicAdd(&h[d0.y >> shift], 1);
        atomicAdd(&h[d0.z >> shift], 1);
        atomicAdd(&h[d0.w >> shift], 1);
        atomicAdd(&h[d1.x >> shift], 1);
        atomicAdd(&h[d1.y >> shift], 1);
        atomicAdd(&h[d1.z >> shift], 1);
        atomicAdd(&h[d1.w >> shift], 1);
    }
    __syncthreads();
    if (t < nbk && h[t]) gbase[t] = (bkoff + t) * bkcap + atomicAdd(&cur[hoff + t], h[t]);
    if (t < 256) sc[t] = (t < nbk) ? h[t] : 0;
    __syncthreads();
    for (int s = 1; s < 256; s <<= 1) {
        int y = (t < 256 && t >= s) ? sc[t - s] : 0;
        __syncthreads();
        if (t < 256) sc[t] += y;
        __syncthreads();
    }
    if (t < nbk) pref[t] = sc[t] - h[t];
    __syncthreads();

    if (ok) {
        #define BIN(dv, sv) { int k = (dv) >> shift; \
            int l = atomicAdd(&csr[k], 1); \
            le[pref[k] + l] = ((unsigned long long)(unsigned int)(dv) << 32) | (unsigned int)(sv); }
        BIN(d0.x, s0.x) BIN(d0.y, s0.y) BIN(d0.z, s0.z) BIN(d0.w, s0.w)
        BIN(d1.x, s1.x) BIN(d1.y, s1.y) BIN(d1.z, s1.z) BIN(d1.w, s1.w)
        #undef BIN
    }
    __syncthreads();

    int n_e = NE - bb * EPB; if (n_e > EPB) n_e = EPB;
    for (int i = t; i < n_e; i += 512) {
        unsigned long long e = le[i];
        int k = (int)(e >> 32) >> shift;
        bedges[(size_t)gbase[k] + (i - pref[k])] = e;
    }
}

// ---- per-bucket ELL build with LDS cursors (plain global stores only) ----
__global__ __launch_bounds__(1024)
void radix_build(const unsigned long long* __restrict__ bedges1, const int* __restrict__ cur,
                 int* __restrict__ cnt_t2c, int* __restrict__ cols_t2c,
                 int* __restrict__ cnt_t2d, int* __restrict__ cols_t2d) {
    __shared__ int lc[2048];
    int t = threadIdx.x, k = blockIdx.x;     // 0..195 global bucket id
    int rel = k >= 98 ? 1 : 0;
    int shift = rel ? 10 : 11;
    int range = 1 << shift;
    int noff = (rel ? (k - 98) : k) << shift;
    int nN = rel ? ND : NC;
    int* cnt = rel ? cnt_t2d : cnt_t2c;
    int* cols = rel ? cols_t2d : cols_t2c;
    int cap = rel ? CAP_T2D : CAP_T2C;
    int e0 = k * CAP_BK1;
    int e1 = e0 + cur[k];
    for (int i = t; i < range; i += 1024) lc[i] = 0;
    __syncthreads();
    for (int i = e0 + t; i < e1; i += 1024) {
        unsigned long long e = bedges1[i];
        int d = (int)(e >> 32);
        int s = (int)(e & 0xffffffffu);
        int l = atomicAdd(&lc[d - noff], 1);           // LDS atomic
        if (l < cap) cols[(size_t)d * cap + l] = s;    // plain store, L2 window
    }
    __syncthreads();
    for (int i = t; i < range; i += 1024) {
        int gn = noff + i;
        if (gn < nN) cnt[gn] = lc[i];
    }
}

#define NBGM_C 3125   // NC/64
#define NBGM_D 1563   // ceil(ND/64)

// ---- gather-mean: wave = 8 nodes, 2 bf16 rows per VMEM instr; bf16 means out ----
__global__ __launch_bounds__(512)
void gather_mean(const unsigned int* __restrict__ Xb,
                 const int* __restrict__ cnt_c, const int* __restrict__ cols_c,
                 const int* __restrict__ cnt_d, const int* __restrict__ cols_d,
                 unsigned int* __restrict__ mB) {
    int t = threadIdx.x;
    int lane = t & 63;
    int w = t >> 6;            // 8 waves
    int half = lane >> 5;
    int li = lane & 31;

    int bn, nNodes, cap;
    const int* cnt; const int* cols; unsigned int* mP;
    if (blockIdx.x < NBGM_C) {
        bn = blockIdx.x * 64; nNodes = NC; cap = CAP_T2C;
        cnt = cnt_c; cols = cols_c; mP = mB;
    } else {
        bn = (blockIdx.x - NBGM_C) * 64; nNodes = ND; cap = CAP_T2D;
        cnt = cnt_d; cols = cols_d; mP = mB + (size_t)NC * 32;
    }

    int gnb = bn + w * 8;
    int cval = 0;
    if (lane < 8 && gnb + lane < nNodes) cval = cnt[gnb + lane];

    int cc[8], mm[8], cv[8];
#pragma unroll
    for (int r = 0; r < 8; ++r) {
        cc[r] = __shfl(cval, r);
        mm[r] = cc[r] < cap ? cc[r] : cap;
    }
#pragma unroll
    for (int r = 0; r < 8; ++r) {
        int gn = gnb + r;
        cv[r] = (lane < mm[r] && gn < nNodes) ? cols[(size_t)gn * cap + lane] : 0;
    }

    int maxm = 0;
#pragma unroll
    for (int r = 0; r < 8; ++r) maxm = maxm > mm[r] ? maxm : mm[r];

    float ax[8], ay[8];
#pragma unroll
    for (int r = 0; r < 8; ++r) { ax[r] = 0.0f; ay[r] = 0.0f; }

    for (int j = 0; j < maxm; j += 2) {
#pragma unroll
        for (int r = 0; r < 8; ++r) {
            int sA = __shfl(cv[r], j);
            int sB = __shfl(cv[r], j + 1);
            int src = half ? sB : sA;
            unsigned int v = 0;
            if (j + half < mm[r]) v = Xb[(size_t)src * 32 + li];
            ax[r] += __uint_as_float(v << 16);
            ay[r] += __uint_as_float(v & 0xffff0000u);
        }
    }

#pragma unroll
    for (int r = 0; r < 8; ++r) {
        float fx = ax[r] + __shfl_xor(ax[r], 32);
        float fy = ay[r] + __shfl_xor(ay[r], 32);
        float inv = cc[r] > 0 ? 1.0f / (float)cc[r] : 0.0f;
        ax[r] = fx * inv; ay[r] = fy * inv;
    }
    // store bf16-packed: pair (r, r+1) -> one 256B wave store (2 rows)
    unsigned int u;
#pragma unroll
    for (int r = 0; r < 8; r += 2) {
        int gn = gnb + r + half;
        float vx = half ? ax[r + 1] : ax[r];
        float vy = half ? ay[r + 1] : ay[r];
        unsigned int pv = BFP(vx) | (BFP(vy) << 16);
        if (gn < nNodes) mP[(size_t)gn * 32 + li] = pv;
    }
}

#define NBX_C 3125    // NC/64
#define NBX_D 1563    // ceil(ND/64)

// ---- xform64: p = lrelu(mask(mean @ W1r + b1r)) @ Wc + bc  (64-node tile) ----
__global__ __launch_bounds__(512)
void xform64(const unsigned int* __restrict__ mB,
             const int* __restrict__ cnt_c, const int* __restrict__ cnt_d,
             const float* __restrict__ W1, const float* __restrict__ b1,
             const float* __restrict__ Wc, const float* __restrict__ bc,
             float* __restrict__ Pc, float* __restrict__ Pd) {
    __shared__ float Xs[64][65];
    __shared__ float Wl[64][68];
    __shared__ float msk[64];
    int t = threadIdx.x;

    int bn, nNodes; const unsigned int* mrow; const int* cnt;
    const float* W1r; const float* b1r; const float* Wcr; const float* bcr;
    float* P;
    if (blockIdx.x < NBX_C) {
        bn = blockIdx.x * 64; nNodes = NC;
        mrow = mB; cnt = cnt_c;
        W1r = W1 + 1 * H * H; b1r = b1 + 1 * H; Wcr = Wc; bcr = bc; P = Pc;
    } else {
        bn = (blockIdx.x - NBX_C) * 64; nNodes = ND;
        mrow = mB + (size_t)NC * 32; cnt = cnt_d;
        W1r = W1 + 3 * H * H; b1r = b1 + 3 * H; Wcr = Wc + 128; bcr = bc + 2; P = Pd;
    }

    {   // stage means tile (64 nodes x 32 uints, bf16x2) and W (64x64 f32)
        int nl = t >> 3, seg = t & 7;
        int gn = bn + nl;
        uint4 v = make_uint4(0, 0, 0, 0);
        if (gn < nNodes) v = ((const uint4*)(mrow + (size_t)gn * 32))[seg];
        float* xr = &Xs[nl][seg * 8];
        xr[0] = __uint_as_float(v.x << 16); xr[1] = __uint_as_float(v.x & 0xffff0000u);
        xr[2] = __uint_as_float(v.y << 16); xr[3] = __uint_as_float(v.y & 0xffff0000u);
        xr[4] = __uint_as_float(v.z << 16); xr[5] = __uint_as_float(v.z & 0xffff0000u);
        xr[6] = __uint_as_float(v.w << 16); xr[7] = __uint_as_float(v.w & 0xffff0000u);
        for (int q = t; q < 1024; q += 512) {
            int kk = q >> 4, s2 = q & 15;
            *(float4*)&Wl[kk][s2 * 4] = *(const float4*)(W1r + kk * H + s2 * 4);
        }
        if (t < 64) msk[t] = (bn + t < nNodes && cnt[bn + t] > 0) ? 1.0f : 0.0f;
    }
    __syncthreads();

    // phase B: thread = (node t>>3, cols (t&7)*8 .. +7)
    int nl = t >> 3;           // 0..63
    int c0 = (t & 7) * 8;
    float4 ba = *(const float4*)(b1r + c0);
    float4 bb4 = *(const float4*)(b1r + c0 + 4);
    float h0 = ba.x, h1 = ba.y, h2 = ba.z, h3 = ba.w;
    float h4 = bb4.x, h5 = bb4.y, h6 = bb4.z, h7 = bb4.w;
#pragma unroll
    for (int k = 0; k < H; ++k) {
        float xv = Xs[nl][k];
        float4 wa = *(const float4*)&Wl[k][c0];
        float4 wb = *(const float4*)&Wl[k][c0 + 4];
        h0 = fmaf(xv, wa.x, h0); h1 = fmaf(xv, wa.y, h1);
        h2 = fmaf(xv, wa.z, h2); h3 = fmaf(xv, wa.w, h3);
        h4 = fmaf(xv, wb.x, h4); h5 = fmaf(xv, wb.y, h5);
        h6 = fmaf(xv, wb.z, h6); h7 = fmaf(xv, wb.w, h7);
    }
    float m = msk[nl];
    h0 = (h0 > 0.f ? h0 : 0.01f * h0) * m;
    h1 = (h1 > 0.f ? h1 : 0.01f * h1) * m;
    h2 = (h2 > 0.f ? h2 : 0.01f * h2) * m;
    h3 = (h3 > 0.f ? h3 : 0.01f * h3) * m;
    h4 = (h4 > 0.f ? h4 : 0.01f * h4) * m;
    h5 = (h5 > 0.f ? h5 : 0.01f * h5) * m;
    h6 = (h6 > 0.f ? h6 : 0.01f * h6) * m;
    h7 = (h7 > 0.f ? h7 : 0.01f * h7) * m;
    float4 wc0 = *(const float4*)(Wcr + c0 * 2);
    float4 wc1 = *(const float4*)(Wcr + c0 * 2 + 4);
    float4 wc2 = *(const float4*)(Wcr + c0 * 2 + 8);
    float4 wc3 = *(const float4*)(Wcr + c0 * 2 + 12);
    float p0 = h0 * wc0.x + h1 * wc0.z + h2 * wc1.x + h3 * wc1.z
             + h4 * wc2.x + h5 * wc2.z + h6 * wc3.x + h7 * wc3.z;
    float p1 = h0 * wc0.y + h1 * wc0.w + h2 * wc1.y + h3 * wc1.w
             + h4 * wc2.y + h5 * wc2.w + h6 * wc3.y + h7 * wc3.w;
#pragma unroll
    for (int off = 1; off < 8; off <<= 1) {
        p0 += __shfl_xor(p0, off);
        p1 += __shfl_xor(p1, off);
    }
    int gn = bn + nl;
    if ((t & 7) == 0 && gn < nNodes) {
        float2 o = make_float2(p0 + bcr[0], p1 + bcr[1]);
        *(float2*)(P + 2 * (size_t)gn) = o;
    }
}

// ---- pack p into fixed-point uint64 with embedded degree count ----
__device__ __forceinline__ unsigned long long pack_p(const float* __restrict__ P, int s) {
    float2 pv = *(const float2*)(P + 2 * (size_t)s);
    float a = fminf(fmaxf(pv.x, -3.99f), 3.99f);
    float b = fminf(fmaxf(pv.y, -3.99f), 3.99f);
    unsigned int ia = (unsigned int)(__float2int_rn(a * PACK_SCALE) + PACK_BIAS);
    unsigned int ib = (unsigned int)(__float2int_rn(b * PACK_SCALE) + PACK_BIAS);
    return (1ULL << 52) | ((unsigned long long)ia << 26) | (unsigned long long)ib;
}

// ---- layer-2 agg: one block per target-bucket; LDS u64 fixed-point accum ----
__global__ __launch_bounds__(1024)
void agg_out(const unsigned long long* __restrict__ bedges2, const int* __restrict__ cur,
             const float* __restrict__ Pc, const float* __restrict__ Pd,
             const float* __restrict__ bout, float* __restrict__ out) {
    __shared__ unsigned long long accC[2048], accD[2048];
    int t = threadIdx.x, k = blockIdx.x;
    int noff = k << 11;
    int range = NT - noff; if (range > 2048) range = 2048;
    for (int i = t; i < 2048; i += 1024) { accC[i] = 0ULL; accD[i] = 0ULL; }
    __syncthreads();

    int e0 = k * CAP_BK2, e1 = e0 + cur[OFF_C2T + k];
    for (int i = e0 + t; i < e1; i += 1024) {
        unsigned long long e = bedges2[i];
        int d = (int)(e >> 32);
        int s = (int)(e & 0xffffffffu);
        atomicAdd(&accC[d - noff], pack_p(Pc, s));     // LDS u64 atomic
    }
    int f0 = (245 + k) * CAP_BK2, f1 = f0 + cur[OFF_D2T + k];
    for (int i = f0 + t; i < f1; i += 1024) {
        unsigned long long e = bedges2[i];
        int d = (int)(e >> 32);
        int s = (int)(e & 0xffffffffu);
        atomicAdd(&accD[d - noff], pack_p(Pd, s));
    }
    __syncthreads();

    float bo0 = bout[0], bo1 = bout[1];
    const float inv_s = 1.0f / PACK_SCALE;
    for (int i = t; i < range; i += 1024) {
        unsigned long long xc = accC[i];
        unsigned long long xd = accD[i];
        int dc = (int)(xc >> 52);
        int dd = (int)(xd >> 52);
        float ic = dc > 0 ? 1.0f / (float)dc : 0.0f;
        float id = dd > 0 ? 1.0f / (float)dd : 0.0f;
        float c0 = (float)((long long)((xc >> 26) & FIELD_MASK) - (long long)dc * PACK_BIAS);
        float c1 = (float)((long long)(xc & FIELD_MASK) - (long long)dc * PACK_BIAS);
        float d0 = (float)((long long)((xd >> 26) & FIELD_MASK) - (long long)dd * PACK_BIAS);
        float d1 = (float)((long long)(xd & FIELD_MASK) - (long long)dd * PACK_BIAS);
        float2 o;
        o.x = bo0 + (c0 * ic + d0 * id) * inv_s;
        o.y = bo1 + (c1 * ic + d1 * id) * inv_s;
        *(float2*)(out + 2 * (size_t)(noff + i)) = o;
    }
}

extern "C" void kernel_launch(void* const* d_in, const int* in_sizes, int n_in,
                              void* d_out, int out_size, void* d_ws, size_t ws_size,
                              hipStream_t stream) {
    const float* features = (const float*)d_in[0];
    const float* W1 = (const float*)d_in[3];
    const float* b1 = (const float*)d_in[4];
    const float* W2 = (const float*)d_in[5];
    const float* b2 = (const float*)d_in[6];
    const float* W_out = (const float*)d_in[7];
    const float* b_out = (const float*)d_in[8];
    const int* src_c2t = (const int*)d_in[9];
    const int* dst_c2t = (const int*)d_in[10];
    const int* src_t2c = (const int*)d_in[11];
    const int* dst_t2c = (const int*)d_in[12];
    const int* src_d2t = (const int*)d_in[13];
    const int* dst_d2t = (const int*)d_in[14];
    const int* src_t2d = (const int*)d_in[15];
    const int* dst_t2d = (const int*)d_in[16];
    float* out = (float*)d_out;

    // ---- workspace carve ----
    char* w = (char*)d_ws;
    int* cur = (int*)w;                           w += 1024 * 4;   // ZERO region (4 KB)
    size_t zero_bytes = 1024 * 4;
    int* cnt_t2c = (int*)w;                       w += (size_t)NC * 4;
    int* cnt_t2d = (int*)w;                       w += (size_t)ND * 4;
    int* cols_t2c = (int*)w;                      w += (size_t)NC * CAP_T2C * 4;
    int* cols_t2d = (int*)w;                      w += (size_t)ND * CAP_T2D * 4;
    float* p_c = (float*)w;                       w += (size_t)NC * 2 * 4;
    float* p_d = (float*)w;                       w += (size_t)ND * 2 * 4;
    float* Wc = (float*)w;                        w += 256 * 4;
    float* bc = (float*)w;                        w += 16;
    unsigned long long* bedges1 = (unsigned long long*)w;  w += (size_t)196 * CAP_BK1 * 8;  // 18.5 MB
    unsigned long long* bedges2 = (unsigned long long*)w;  w += (size_t)490 * CAP_BK2 * 8;  // 19.1 MB
    unsigned int* Xb = (unsigned int*)w;          w += (size_t)NT * H * 2;                  // 64 MB
    unsigned int* mB = (unsigned int*)w;          w += ((size_t)(NC + ND) + 64) * 32 * 4;   // 38.4 MB

    hipMemsetAsync(d_ws, 0, zero_bytes, stream);

    // radix scatter (all 4 relations) + feature compress + prep_fold, one grid
    scatter_compress<<<4 * BPR + CB512 + 1, 512, 0, stream>>>(
        src_t2c, dst_t2c, src_t2d, dst_t2d,
        src_c2t, dst_c2t, src_d2t, dst_d2t,
        cur, bedges1, bedges2,
        features, Xb, W2, b2, W_out, Wc, bc);

    radix_build<<<196, 1024, 0, stream>>>(bedges1, cur,
                                          cnt_t2c, cols_t2c, cnt_t2d, cols_t2d);

    gather_mean<<<NBGM_C + NBGM_D, 512, 0, stream>>>(
        Xb, cnt_t2c, cols_t2c, cnt_t2d, cols_t2d, mB);

    xform64<<<NBX_C + NBX_D, 512, 0, stream>>>(
        mB, cnt_t2c, cnt_t2d, W1, b1, Wc, bc, p_c, p_d);

    agg_out<<<NBK_MAX, 1024, 0, stream>>>(bedges2, cur, p_c, p_d, b_out, out);
}

// Round 14
// 229.404 us; speedup vs baseline: 1.0487x; 1.0487x over previous
//
#include <hip/hip_runtime.h>
#include <hip/hip_bf16.h>

// HeteroRGCN:
//   p_c = lrelu(mask(mean_t2c(x) @ W1[1] + b1[1])) @ (W2[0]@W_out) + b2[0]@W_out
//   p_d = same with W1[3], W2[2]
//   out[t] = b_out + mean_c2t(p_c) + mean_d2t(p_d)
// All random aggregation via LDS atomics + bucket sort (device atomics obey
// a ~48us/M random-line-op law). Fixed per-bucket capacities -> arithmetic
// bucket bases. gather/transform split (fusion kills random-fetch BW, r12);
// transform = 4x4 register tile (r13's 8-col variant was LDS-pipe-bound).

#define NT 500000
#define NC 200000
#define ND 100000
#define NE 1000000
#define H  64
#define CAP_T2C 32      // per-node ELL cap, dst NC (lambda=5)
#define CAP_T2D 48      // per-node ELL cap, dst ND (lambda=10)

#define PACK_SCALE 65536.0f
#define PACK_BIAS  262144   // 4 * 65536
#define FIELD_MASK 0x3FFFFFFULL

// radix: rel 0 t2c (shift11, 98 bk), rel 1 t2d (shift10, 98 bk),
//        rel 2 c2t (shift10, 489 bk), rel 3 d2t (shift10, 489 bk)
#define NBK_MAX 489
#define NBK2 489
#define OFF_C2T 196         // cur[] index offsets
#define OFF_D2T 685         // 196 + 489
#define EPB 4096
#define BPR 245             // ceil(NE/EPB)
#define CAP_BK1 11776       // bucket capacity, L1 (exp 10240, +15 sigma)
#define CAP_BK2 2688        // bucket capacity, L2 (exp 2048, +14 sigma)

#define CB512 7813          // compress blocks: ceil(4,000,000 / 512)

__device__ __forceinline__ void rel_params(int rel, int& shift, int& hoff, int& nbk) {
    shift = (rel == 0) ? 11 : 10;
    hoff = (rel == 0) ? 0 : (rel == 1) ? 98 : (rel == 2) ? OFF_C2T : OFF_D2T;
    nbk = (rel < 2) ? 98 : NBK2;
}

#define BFP(x) (u = __float_as_uint(x), (u + 0x7fffu + ((u >> 16) & 1u)) >> 16)

// ---- fused: radix scatter (implicit bases) + feature compress + prep_fold ----
__global__ __launch_bounds__(512)
void scatter_compress(const int* __restrict__ st2c, const int* __restrict__ dt2c,
                      const int* __restrict__ st2d, const int* __restrict__ dt2d,
                      const int* __restrict__ sc2t, const int* __restrict__ dc2t,
                      const int* __restrict__ sd2t, const int* __restrict__ dd2t,
                      int* __restrict__ cur,
                      unsigned long long* __restrict__ bedges1,
                      unsigned long long* __restrict__ bedges2,
                      const float* __restrict__ X, unsigned int* __restrict__ Xb,
                      const float* __restrict__ W2, const float* __restrict__ b2,
                      const float* __restrict__ Wout,
                      float* __restrict__ Wc, float* __restrict__ bc) {
    __shared__ unsigned long long le[EPB];
    __shared__ int h[NBK_MAX], pref[NBK_MAX], gbase[NBK_MAX], csr[NBK_MAX];
    __shared__ int sc[512];
    int t = threadIdx.x, b = blockIdx.x;

    if (b >= 4 * BPR) {
        int cb = b - 4 * BPR;
        if (cb < CB512) {
            size_t idx = (size_t)cb * 512 + t;
            if (idx < 4000000) {
                const float4 f0 = ((const float4*)X)[idx * 2];
                const float4 f1 = ((const float4*)X)[idx * 2 + 1];
                uint4 o;
                unsigned int u;
                o.x = BFP(f0.x) | (BFP(f0.y) << 16);
                o.y = BFP(f0.z) | (BFP(f0.w) << 16);
                o.z = BFP(f1.x) | (BFP(f1.y) << 16);
                o.w = BFP(f1.z) | (BFP(f1.w) << 16);
                ((uint4*)Xb)[idx] = o;
            }
        } else if (t < 256) {
            // prep_fold: Wc[rel][k][o] = sum_j W2[rel*2][k][j] * Wout[j][o]
            int rel = t >> 7;
            int rem = t & 127;
            int k = rem >> 1, o = rem & 1;
            const float* W2r = W2 + (rel ? 2 : 0) * H * H;
            float s = 0.0f;
            for (int j = 0; j < H; ++j) s += W2r[k * H + j] * Wout[j * 2 + o];
            Wc[rel * 128 + k * 2 + o] = s;
            if (rem < 4) {
                int r2 = rem >> 1, o2 = rem & 1;
                const float* b2r = b2 + (r2 ? 2 : 0) * H;
                float sb = 0.0f;
                for (int j = 0; j < H; ++j) sb += b2r[j] * Wout[j * 2 + o2];
                bc[r2 * 2 + o2] = sb;
            }
        }
        return;
    }

    int rel = b / BPR;
    int bb = b - rel * BPR;
    const int* sp = (rel == 0) ? st2c : (rel == 1) ? st2d : (rel == 2) ? sc2t : sd2t;
    const int* dp = (rel == 0) ? dt2c : (rel == 1) ? dt2d : (rel == 2) ? dc2t : dd2t;
    int shift, hoff, nbk;
    rel_params(rel, shift, hoff, nbk);
    unsigned long long* bedges = (rel < 2) ? bedges1 : bedges2;
    int bkoff = (rel == 1) ? 98 : (rel == 3) ? NBK2 : 0;
    int bkcap = (rel < 2) ? CAP_BK1 : CAP_BK2;

    for (int i = t; i < nbk; i += 512) { h[i] = 0; csr[i] = 0; }
    __syncthreads();

    int base = bb * EPB + t * 8;
    bool ok = base < NE;
    int4 d0, d1, s0, s1;
    if (ok) {
        d0 = *(const int4*)(dp + base);
        d1 = *(const int4*)(dp + base + 4);
        s0 = *(const int4*)(sp + base);
        s1 = *(const int4*)(sp + base + 4);
        atomicAdd(&h[d0.x >> shift], 1);
        atomicAdd(&h[d0.y >> shift], 1);
        atomicAdd(&h[d0.z >> shift], 1);
        atomicAdd(&h[d0.w >> shift], 1);
        atomicAdd(&h[d1.x >> shift], 1);
        atomicAdd(&h[d1.y >> shift], 1);
        atomicAdd(&h[d1.z >> shift], 1);
        atomicAdd(&h[d1.w >> shift], 1);
    }
    __syncthreads();
    if (t < nbk && h[t]) gbase[t] = (bkoff + t) * bkcap + atomicAdd(&cur[hoff + t], h[t]);
    sc[t] = (t < nbk) ? h[t] : 0;
    __syncthreads();
    for (int s = 1; s < 512; s <<= 1) {
        int y = (t >= s) ? sc[t - s] : 0;
        __syncthreads();
        sc[t] += y;
        __syncthreads();
    }
    if (t < nbk) pref[t] = sc[t] - h[t];
    __syncthreads();

    if (ok) {
        #define BIN(dv, sv) { int k = (dv) >> shift; \
            int l = atomicAdd(&csr[k], 1); \
            le[pref[k] + l] = ((unsigned long long)(unsigned int)(dv) << 32) | (unsigned int)(sv); }
        BIN(d0.x, s0.x) BIN(d0.y, s0.y) BIN(d0.z, s0.z) BIN(d0.w, s0.w)
        BIN(d1.x, s1.x) BIN(d1.y, s1.y) BIN(d1.z, s1.z) BIN(d1.w, s1.w)
        #undef BIN
    }
    __syncthreads();

    int n_e = NE - bb * EPB; if (n_e > EPB) n_e = EPB;
    for (int i = t; i < n_e; i += 512) {
        unsigned long long e = le[i];
        int k = (int)(e >> 32) >> shift;
        bedges[(size_t)gbase[k] + (i - pref[k])] = e;
    }
}

// ---- per-bucket ELL build with LDS cursors (plain global stores only) ----
__global__ __launch_bounds__(1024)
void radix_build(const unsigned long long* __restrict__ bedges1, const int* __restrict__ cur,
                 int* __restrict__ cnt_t2c, int* __restrict__ cols_t2c,
                 int* __restrict__ cnt_t2d, int* __restrict__ cols_t2d) {
    __shared__ int lc[2048];
    int t = threadIdx.x, k = blockIdx.x;     // 0..195 global bucket id
    int rel = k >= 98 ? 1 : 0;
    int shift = rel ? 10 : 11;
    int range = 1 << shift;
    int noff = (rel ? (k - 98) : k) << shift;
    int nN = rel ? ND : NC;
    int* cnt = rel ? cnt_t2d : cnt_t2c;
    int* cols = rel ? cols_t2d : cols_t2c;
    int cap = rel ? CAP_T2D : CAP_T2C;
    int e0 = k * CAP_BK1;
    int e1 = e0 + cur[k];
    for (int i = t; i < range; i += 1024) lc[i] = 0;
    __syncthreads();
    for (int i = e0 + t; i < e1; i += 1024) {
        unsigned long long e = bedges1[i];
        int d = (int)(e >> 32);
        int s = (int)(e & 0xffffffffu);
        int l = atomicAdd(&lc[d - noff], 1);           // LDS atomic
        if (l < cap) cols[(size_t)d * cap + l] = s;    // plain store, L2 window
    }
    __syncthreads();
    for (int i = t; i < range; i += 1024) {
        int gn = noff + i;
        if (gn < nN) cnt[gn] = lc[i];
    }
}

#define NBGM_C 3125   // NC/64
#define NBGM_D 1563   // ceil(ND/64)

// ---- gather-mean: wave = 8 nodes, 2 bf16 rows per VMEM instr; bf16 means out ----
__global__ __launch_bounds__(512)
void gather_mean(const unsigned int* __restrict__ Xb,
                 const int* __restrict__ cnt_c, const int* __restrict__ cols_c,
                 const int* __restrict__ cnt_d, const int* __restrict__ cols_d,
                 unsigned int* __restrict__ mB) {
    int t = threadIdx.x;
    int lane = t & 63;
    int w = t >> 6;            // 8 waves
    int half = lane >> 5;
    int li = lane & 31;

    int bn, nNodes, cap;
    const int* cnt; const int* cols; unsigned int* mP;
    if (blockIdx.x < NBGM_C) {
        bn = blockIdx.x * 64; nNodes = NC; cap = CAP_T2C;
        cnt = cnt_c; cols = cols_c; mP = mB;
    } else {
        bn = (blockIdx.x - NBGM_C) * 64; nNodes = ND; cap = CAP_T2D;
        cnt = cnt_d; cols = cols_d; mP = mB + (size_t)NC * 32;
    }

    int gnb = bn + w * 8;
    int cval = 0;
    if (lane < 8 && gnb + lane < nNodes) cval = cnt[gnb + lane];

    int cc[8], mm[8], cv[8];
#pragma unroll
    for (int r = 0; r < 8; ++r) {
        cc[r] = __shfl(cval, r);
        mm[r] = cc[r] < cap ? cc[r] : cap;
    }
#pragma unroll
    for (int r = 0; r < 8; ++r) {
        int gn = gnb + r;
        cv[r] = (lane < mm[r] && gn < nNodes) ? cols[(size_t)gn * cap + lane] : 0;
    }

    int maxm = 0;
#pragma unroll
    for (int r = 0; r < 8; ++r) maxm = maxm > mm[r] ? maxm : mm[r];

    float ax[8], ay[8];
#pragma unroll
    for (int r = 0; r < 8; ++r) { ax[r] = 0.0f; ay[r] = 0.0f; }

    for (int j = 0; j < maxm; j += 2) {
#pragma unroll
        for (int r = 0; r < 8; ++r) {
            int sA = __shfl(cv[r], j);
            int sB = __shfl(cv[r], j + 1);
            int src = half ? sB : sA;
            unsigned int v = 0;
            if (j + half < mm[r]) v = Xb[(size_t)src * 32 + li];
            ax[r] += __uint_as_float(v << 16);
            ay[r] += __uint_as_float(v & 0xffff0000u);
        }
    }

#pragma unroll
    for (int r = 0; r < 8; ++r) {
        float fx = ax[r] + __shfl_xor(ax[r], 32);
        float fy = ay[r] + __shfl_xor(ay[r], 32);
        float inv = cc[r] > 0 ? 1.0f / (float)cc[r] : 0.0f;
        ax[r] = fx * inv; ay[r] = fy * inv;
    }
    // store bf16-packed: pair (r, r+1) -> one 256B wave store (2 rows)
    unsigned int u;
#pragma unroll
    for (int r = 0; r < 8; r += 2) {
        int gn = gnb + r + half;
        float vx = half ? ax[r + 1] : ax[r];
        float vy = half ? ay[r + 1] : ay[r];
        unsigned int pv = BFP(vx) | (BFP(vy) << 16);
        if (gn < nNodes) mP[(size_t)gn * 32 + li] = pv;
    }
}

#define NBX_C 3125    // NC/64
#define NBX_D 1563    // ceil(ND/64)

// ---- xform_tile: 4x4 register-tile transform (r2 structure, bf16 means in) ----
// 256 threads, 64 nodes/block. Xt transposed [k][node] for 4-node float4 reads.
__global__ __launch_bounds__(256)
void xform_tile(const unsigned int* __restrict__ mB,
                const int* __restrict__ cnt_c, const int* __restrict__ cnt_d,
                const float* __restrict__ W1, const float* __restrict__ b1,
                const float* __restrict__ Wc, const float* __restrict__ bc,
                float* __restrict__ Pc, float* __restrict__ Pd) {
    __shared__ float Xt[64][68];   // [k][node]
    __shared__ float Wl[64][68];   // [k][col]
    __shared__ float msk[64];
    int t = threadIdx.x;

    int bn, nNodes; const unsigned int* mrow; const int* cnt;
    const float* W1r; const float* b1r; const float* Wcr; const float* bcr;
    float* P;
    if (blockIdx.x < NBX_C) {
        bn = blockIdx.x * 64; nNodes = NC;
        mrow = mB; cnt = cnt_c;
        W1r = W1 + 1 * H * H; b1r = b1 + 1 * H; Wcr = Wc; bcr = bc; P = Pc;
    } else {
        bn = (blockIdx.x - NBX_C) * 64; nNodes = ND;
        mrow = mB + (size_t)NC * 32; cnt = cnt_d;
        W1r = W1 + 3 * H * H; b1r = b1 + 3 * H; Wcr = Wc + 128; bcr = bc + 2; P = Pd;
    }

    {   // stage means transposed: thread = (node t&63, k-range (t>>6)*16..+15)
        int node = t & 63, seg = t >> 6;
        int gn = bn + node;
        uint4 v0 = make_uint4(0, 0, 0, 0), v1 = make_uint4(0, 0, 0, 0);
        if (gn < nNodes) {
            const uint4* rp = (const uint4*)(mrow + (size_t)gn * 32);
            v0 = rp[seg * 2];
            v1 = rp[seg * 2 + 1];
        }
        int k0 = seg * 16;
        Xt[k0 + 0][node] = __uint_as_float(v0.x << 16);
        Xt[k0 + 1][node] = __uint_as_float(v0.x & 0xffff0000u);
        Xt[k0 + 2][node] = __uint_as_float(v0.y << 16);
        Xt[k0 + 3][node] = __uint_as_float(v0.y & 0xffff0000u);
        Xt[k0 + 4][node] = __uint_as_float(v0.z << 16);
        Xt[k0 + 5][node] = __uint_as_float(v0.z & 0xffff0000u);
        Xt[k0 + 6][node] = __uint_as_float(v0.w << 16);
        Xt[k0 + 7][node] = __uint_as_float(v0.w & 0xffff0000u);
        Xt[k0 + 8][node] = __uint_as_float(v1.x << 16);
        Xt[k0 + 9][node] = __uint_as_float(v1.x & 0xffff0000u);
        Xt[k0 + 10][node] = __uint_as_float(v1.y << 16);
        Xt[k0 + 11][node] = __uint_as_float(v1.y & 0xffff0000u);
        Xt[k0 + 12][node] = __uint_as_float(v1.z << 16);
        Xt[k0 + 13][node] = __uint_as_float(v1.z & 0xffff0000u);
        Xt[k0 + 14][node] = __uint_as_float(v1.w << 16);
        Xt[k0 + 15][node] = __uint_as_float(v1.w & 0xffff0000u);
        for (int q = t; q < 1024; q += 256) {
            int kk = q >> 4, s2 = q & 15;
            *(float4*)&Wl[kk][s2 * 4] = *(const float4*)(W1r + kk * H + s2 * 4);
        }
        if (t < 64) msk[t] = (bn + t < nNodes && cnt[bn + t] > 0) ? 1.0f : 0.0f;
    }
    __syncthreads();

    // compute: thread = (nodes (t>>4)*4..+3, cols (t&15)*4..+3)
    int tj = t & 15;
    int ti = t >> 4;
    float4 b4 = *(const float4*)(b1r + tj * 4);
    float a4[4][4];
#pragma unroll
    for (int r = 0; r < 4; ++r) {
        a4[r][0] = b4.x; a4[r][1] = b4.y; a4[r][2] = b4.z; a4[r][3] = b4.w;
    }
#pragma unroll
    for (int k = 0; k < H; ++k) {
        float4 a = *(const float4*)&Xt[k][ti * 4];
        float4 b = *(const float4*)&Wl[k][tj * 4];
        a4[0][0] = fmaf(a.x, b.x, a4[0][0]); a4[0][1] = fmaf(a.x, b.y, a4[0][1]);
        a4[0][2] = fmaf(a.x, b.z, a4[0][2]); a4[0][3] = fmaf(a.x, b.w, a4[0][3]);
        a4[1][0] = fmaf(a.y, b.x, a4[1][0]); a4[1][1] = fmaf(a.y, b.y, a4[1][1]);
        a4[1][2] = fmaf(a.y, b.z, a4[1][2]); a4[1][3] = fmaf(a.y, b.w, a4[1][3]);
        a4[2][0] = fmaf(a.z, b.x, a4[2][0]); a4[2][1] = fmaf(a.z, b.y, a4[2][1]);
        a4[2][2] = fmaf(a.z, b.z, a4[2][2]); a4[2][3] = fmaf(a.z, b.w, a4[2][3]);
        a4[3][0] = fmaf(a.w, b.x, a4[3][0]); a4[3][1] = fmaf(a.w, b.y, a4[3][1]);
        a4[3][2] = fmaf(a.w, b.z, a4[3][2]); a4[3][3] = fmaf(a.w, b.w, a4[3][3]);
    }

    float4 wca = *(const float4*)(Wcr + tj * 8);       // cols tj*4, tj*4+1
    float4 wcb = *(const float4*)(Wcr + tj * 8 + 4);   // cols tj*4+2, tj*4+3
    float p0[4], p1[4];
#pragma unroll
    for (int r = 0; r < 4; ++r) {
        float m = msk[ti * 4 + r];
        float h0 = a4[r][0], h1 = a4[r][1], h2 = a4[r][2], h3 = a4[r][3];
        h0 = (h0 > 0.f ? h0 : 0.01f * h0) * m;
        h1 = (h1 > 0.f ? h1 : 0.01f * h1) * m;
        h2 = (h2 > 0.f ? h2 : 0.01f * h2) * m;
        h3 = (h3 > 0.f ? h3 : 0.01f * h3) * m;
        p0[r] = h0 * wca.x + h1 * wca.z + h2 * wcb.x + h3 * wcb.z;
        p1[r] = h0 * wca.y + h1 * wca.w + h2 * wcb.y + h3 * wcb.w;
    }
#pragma unroll
    for (int off = 1; off < 16; off <<= 1) {
#pragma unroll
        for (int r = 0; r < 4; ++r) {
            p0[r] += __shfl_xor(p0[r], off);
            p1[r] += __shfl_xor(p1[r], off);
        }
    }
    if (tj == 0) {
#pragma unroll
        for (int r = 0; r < 4; ++r) {
            int gn = bn + ti * 4 + r;
            if (gn < nNodes) {
                float2 o = make_float2(p0[r] + bcr[0], p1[r] + bcr[1]);
                *(float2*)(P + 2 * (size_t)gn) = o;
            }
        }
    }
}

// ---- pack p into fixed-point uint64 with embedded degree count ----
__device__ __forceinline__ unsigned long long pack_p(const float* __restrict__ P, int s) {
    float2 pv = *(const float2*)(P + 2 * (size_t)s);
    float a = fminf(fmaxf(pv.x, -3.99f), 3.99f);
    float b = fminf(fmaxf(pv.y, -3.99f), 3.99f);
    unsigned int ia = (unsigned int)(__float2int_rn(a * PACK_SCALE) + PACK_BIAS);
    unsigned int ib = (unsigned int)(__float2int_rn(b * PACK_SCALE) + PACK_BIAS);
    return (1ULL << 52) | ((unsigned long long)ia << 26) | (unsigned long long)ib;
}

// ---- layer-2 agg: one block per 1024-node bucket; LDS u64 fixed-point accum ----
__global__ __launch_bounds__(512)
void agg_out(const unsigned long long* __restrict__ bedges2, const int* __restrict__ cur,
             const float* __restrict__ Pc, const float* __restrict__ Pd,
             const float* __restrict__ bout, float* __restrict__ out) {
    __shared__ unsigned long long accC[1024], accD[1024];
    int t = threadIdx.x, k = blockIdx.x;
    int noff = k << 10;
    int range = NT - noff; if (range > 1024) range = 1024;
    for (int i = t; i < 1024; i += 512) { accC[i] = 0ULL; accD[i] = 0ULL; }
    __syncthreads();

    int e0 = k * CAP_BK2, e1 = e0 + cur[OFF_C2T + k];
    for (int i = e0 + t; i < e1; i += 512) {
        unsigned long long e = bedges2[i];
        int d = (int)(e >> 32);
        int s = (int)(e & 0xffffffffu);
        atomicAdd(&accC[d - noff], pack_p(Pc, s));     // LDS u64 atomic
    }
    int f0 = (NBK2 + k) * CAP_BK2, f1 = f0 + cur[OFF_D2T + k];
    for (int i = f0 + t; i < f1; i += 512) {
        unsigned long long e = bedges2[i];
        int d = (int)(e >> 32);
        int s = (int)(e & 0xffffffffu);
        atomicAdd(&accD[d - noff], pack_p(Pd, s));
    }
    __syncthreads();

    float bo0 = bout[0], bo1 = bout[1];
    const float inv_s = 1.0f / PACK_SCALE;
    for (int i = t; i < range; i += 512) {
        unsigned long long xc = accC[i];
        unsigned long long xd = accD[i];
        int dc = (int)(xc >> 52);
        int dd = (int)(xd >> 52);
        float ic = dc > 0 ? 1.0f / (float)dc : 0.0f;
        float id = dd > 0 ? 1.0f / (float)dd : 0.0f;
        float c0 = (float)((long long)((xc >> 26) & FIELD_MASK) - (long long)dc * PACK_BIAS);
        float c1 = (float)((long long)(xc & FIELD_MASK) - (long long)dc * PACK_BIAS);
        float d0 = (float)((long long)((xd >> 26) & FIELD_MASK) - (long long)dd * PACK_BIAS);
        float d1 = (float)((long long)(xd & FIELD_MASK) - (long long)dd * PACK_BIAS);
        float2 o;
        o.x = bo0 + (c0 * ic + d0 * id) * inv_s;
        o.y = bo1 + (c1 * ic + d1 * id) * inv_s;
        *(float2*)(out + 2 * (size_t)(noff + i)) = o;
    }
}

extern "C" void kernel_launch(void* const* d_in, const int* in_sizes, int n_in,
                              void* d_out, int out_size, void* d_ws, size_t ws_size,
                              hipStream_t stream) {
    const float* features = (const float*)d_in[0];
    const float* W1 = (const float*)d_in[3];
    const float* b1 = (const float*)d_in[4];
    const float* W2 = (const float*)d_in[5];
    const float* b2 = (const float*)d_in[6];
    const float* W_out = (const float*)d_in[7];
    const float* b_out = (const float*)d_in[8];
    const int* src_c2t = (const int*)d_in[9];
    const int* dst_c2t = (const int*)d_in[10];
    const int* src_t2c = (const int*)d_in[11];
    const int* dst_t2c = (const int*)d_in[12];
    const int* src_d2t = (const int*)d_in[13];
    const int* dst_d2t = (const int*)d_in[14];
    const int* src_t2d = (const int*)d_in[15];
    const int* dst_t2d = (const int*)d_in[16];
    float* out = (float*)d_out;

    // ---- workspace carve ----
    char* w = (char*)d_ws;
    int* cur = (int*)w;                           w += 2048 * 4;   // ZERO region (8 KB)
    size_t zero_bytes = 2048 * 4;
    int* cnt_t2c = (int*)w;                       w += (size_t)NC * 4;
    int* cnt_t2d = (int*)w;                       w += (size_t)ND * 4;
    int* cols_t2c = (int*)w;                      w += (size_t)NC * CAP_T2C * 4;
    int* cols_t2d = (int*)w;                      w += (size_t)ND * CAP_T2D * 4;
    float* p_c = (float*)w;                       w += (size_t)NC * 2 * 4;
    float* p_d = (float*)w;                       w += (size_t)ND * 2 * 4;
    float* Wc = (float*)w;                        w += 256 * 4;
    float* bc = (float*)w;                        w += 16;
    unsigned long long* bedges1 = (unsigned long long*)w;  w += (size_t)196 * CAP_BK1 * 8;       // 18.5 MB
    unsigned long long* bedges2 = (unsigned long long*)w;  w += (size_t)(2 * NBK2) * CAP_BK2 * 8; // 21.0 MB
    unsigned int* Xb = (unsigned int*)w;          w += (size_t)NT * H * 2;                  // 64 MB
    unsigned int* mB = (unsigned int*)w;          w += ((size_t)(NC + ND) + 64) * 32 * 4;   // 38.4 MB

    hipMemsetAsync(d_ws, 0, zero_bytes, stream);

    // radix scatter (all 4 relations) + feature compress + prep_fold, one grid
    scatter_compress<<<4 * BPR + CB512 + 1, 512, 0, stream>>>(
        src_t2c, dst_t2c, src_t2d, dst_t2d,
        src_c2t, dst_c2t, src_d2t, dst_d2t,
        cur, bedges1, bedges2,
        features, Xb, W2, b2, W_out, Wc, bc);

    radix_build<<<196, 1024, 0, stream>>>(bedges1, cur,
                                          cnt_t2c, cols_t2c, cnt_t2d, cols_t2d);

    gather_mean<<<NBGM_C + NBGM_D, 512, 0, stream>>>(
        Xb, cnt_t2c, cols_t2c, cnt_t2d, cols_t2d, mB);

    xform_tile<<<NBX_C + NBX_D, 256, 0, stream>>>(
        mB, cnt_t2c, cnt_t2d, W1, b1, Wc, bc, p_c, p_d);

    agg_out<<<NBK2, 512, 0, stream>>>(bedges2, cur, p_c, p_d, b_out, out);
}

// Round 15
// 221.496 us; speedup vs baseline: 1.0862x; 1.0357x over previous
//
#include <hip/hip_runtime.h>
#include <hip/hip_bf16.h>

// HeteroRGCN:
//   p_c = lrelu(mask(mean_t2c(x) @ W1[1] + b1[1])) @ (W2[0]@W_out) + b2[0]@W_out
//   p_d = same with W1[3], W2[2]
//   out[t] = b_out + mean_c2t(p_c) + mean_d2t(p_d)
// All random aggregation via LDS atomics + bucket sort. Edges packed u32
// ((dloc<<19)|src). Wave-shuffle scan (3 barriers vs 18). rel-2/3 scatter
// co-scheduled with gather_mean (independent, both non-device-atomic).

#define NT 500000
#define NC 200000
#define ND 100000
#define NE 1000000
#define H  64
#define CAP_T2C 32      // per-node ELL cap, dst NC (lambda=5)
#define CAP_T2D 48      // per-node ELL cap, dst ND (lambda=10)

#define PACK_SCALE 65536.0f
#define PACK_BIAS  262144   // 4 * 65536
#define FIELD_MASK 0x3FFFFFFULL

// radix: rel 0 t2c (shift11, 98 bk), rel 1 t2d (shift10, 98 bk),
//        rel 2 c2t (shift10, 489 bk), rel 3 d2t (shift10, 489 bk)
#define NBK_MAX 489
#define NBK2 489
#define OFF_C2T 196         // cur[] index offsets
#define OFF_D2T 685         // 196 + 489
#define EPB 4096
#define BPR 245             // ceil(NE/EPB)
#define CAP_BK1 11776       // bucket capacity, L1 (exp 10240, +15 sigma)
#define CAP_BK2 2688        // bucket capacity, L2 (exp 2048, +14 sigma)

#define CB512 7813          // compress blocks: ceil(4,000,000 / 512)

#define NBGM_C 3125   // NC/64
#define NBGM_D 1563   // ceil(ND/64)
#define NBX_C 3125
#define NBX_D 1563

#define BFP(x) (u = __float_as_uint(x), (u + 0x7fffu + ((u >> 16) & 1u)) >> 16)

// ---- shared radix-scatter body: bins EPB edges of one relation chunk ----
__device__ __forceinline__ void scatter_body(
        const int* __restrict__ sp, const int* __restrict__ dp,
        int bb, int rel, int* __restrict__ cur, unsigned int* __restrict__ bedges,
        unsigned long long* le, int* h, int* pref, int* gbase, int* csr,
        int* wsum, int* woff) {
    int t = threadIdx.x;
    int lane = t & 63, w = t >> 6;
    int shift = (rel == 0) ? 11 : 10;
    int nbk = (rel < 2) ? 98 : NBK2;
    int hoff = (rel == 0) ? 0 : (rel == 1) ? 98 : (rel == 2) ? OFF_C2T : OFF_D2T;
    int bkoff = (rel == 1) ? 98 : (rel == 3) ? NBK2 : 0;
    int bkcap = (rel < 2) ? CAP_BK1 : CAP_BK2;

    for (int i = t; i < nbk; i += 512) { h[i] = 0; csr[i] = 0; }
    __syncthreads();                                     // B1

    int base = bb * EPB + t * 8;
    bool ok = base < NE;
    int4 d0, d1, s0, s1;
    if (ok) {
        d0 = *(const int4*)(dp + base);
        d1 = *(const int4*)(dp + base + 4);
        s0 = *(const int4*)(sp + base);
        s1 = *(const int4*)(sp + base + 4);
        atomicAdd(&h[d0.x >> shift], 1);
        atomicAdd(&h[d0.y >> shift], 1);
        atomicAdd(&h[d0.z >> shift], 1);
        atomicAdd(&h[d0.w >> shift], 1);
        atomicAdd(&h[d1.x >> shift], 1);
        atomicAdd(&h[d1.y >> shift], 1);
        atomicAdd(&h[d1.z >> shift], 1);
        atomicAdd(&h[d1.w >> shift], 1);
    }
    __syncthreads();                                     // B2

    int hv = (t < nbk) ? h[t] : 0;
    if (t < nbk && hv) gbase[t] = (bkoff + t) * bkcap + atomicAdd(&cur[hoff + t], hv);
    // wave-shuffle exclusive scan of h -> pref
    int v = hv;
#pragma unroll
    for (int d = 1; d < 64; d <<= 1) {
        int y = __shfl_up(v, d);
        v += (lane >= d) ? y : 0;
    }
    if (lane == 63) wsum[w] = v;
    __syncthreads();                                     // B3
    if (t < 8) {
        int s = 0;
        for (int j = 0; j < t; ++j) s += wsum[j];
        woff[t] = s;
    }
    __syncthreads();                                     // B4
    if (t < nbk) pref[t] = v - hv + woff[w];
    __syncthreads();                                     // B5

    if (ok) {
        #define BIN(dv, sv) { int k = (dv) >> shift; \
            int l = atomicAdd(&csr[k], 1); \
            le[pref[k] + l] = ((unsigned long long)(unsigned int)(dv) << 32) | (unsigned int)(sv); }
        BIN(d0.x, s0.x) BIN(d0.y, s0.y) BIN(d0.z, s0.z) BIN(d0.w, s0.w)
        BIN(d1.x, s1.x) BIN(d1.y, s1.y) BIN(d1.z, s1.z) BIN(d1.w, s1.w)
        #undef BIN
    }
    __syncthreads();                                     // B6

    int n_e = NE - bb * EPB; if (n_e > EPB) n_e = EPB;
    for (int i = t; i < n_e; i += 512) {
        unsigned long long e = le[i];
        unsigned int dst = (unsigned int)(e >> 32);
        unsigned int srcv = (unsigned int)e;
        int k = dst >> shift;
        unsigned int packed = ((dst - ((unsigned int)k << shift)) << 19) | srcv;
        bedges[(size_t)gbase[k] + (i - pref[k])] = packed;   // u32, coalesced runs
    }
}

// ---- k1: scatter rel 0,1 + feature compress + prep_fold ----
__global__ __launch_bounds__(512)
void scatter01_compress(const int* __restrict__ st2c, const int* __restrict__ dt2c,
                        const int* __restrict__ st2d, const int* __restrict__ dt2d,
                        int* __restrict__ cur, unsigned int* __restrict__ bedges1,
                        const float* __restrict__ X, unsigned int* __restrict__ Xb,
                        const float* __restrict__ W2, const float* __restrict__ b2,
                        const float* __restrict__ Wout,
                        float* __restrict__ Wc, float* __restrict__ bc) {
    __shared__ unsigned long long le[EPB];
    __shared__ int h[NBK_MAX], pref[NBK_MAX], gbase[NBK_MAX], csr[NBK_MAX];
    __shared__ int wsum[8], woff[8];
    int t = threadIdx.x, b = blockIdx.x;

    if (b < 2 * BPR) {
        int rel = b / BPR;
        int bb = b - rel * BPR;
        const int* sp = (rel == 0) ? st2c : st2d;
        const int* dp = (rel == 0) ? dt2c : dt2d;
        scatter_body(sp, dp, bb, rel, cur, bedges1, le, h, pref, gbase, csr, wsum, woff);
        return;
    }
    int cb = b - 2 * BPR;
    if (cb < CB512) {
        size_t idx = (size_t)cb * 512 + t;
        if (idx < 4000000) {
            const float4 f0 = ((const float4*)X)[idx * 2];
            const float4 f1 = ((const float4*)X)[idx * 2 + 1];
            uint4 o;
            unsigned int u;
            o.x = BFP(f0.x) | (BFP(f0.y) << 16);
            o.y = BFP(f0.z) | (BFP(f0.w) << 16);
            o.z = BFP(f1.x) | (BFP(f1.y) << 16);
            o.w = BFP(f1.z) | (BFP(f1.w) << 16);
            ((uint4*)Xb)[idx] = o;
        }
    } else if (t < 256) {
        // prep_fold: Wc[rel][k][o] = sum_j W2[rel*2][k][j] * Wout[j][o]
        int rel = t >> 7;
        int rem = t & 127;
        int k = rem >> 1, o = rem & 1;
        const float* W2r = W2 + (rel ? 2 : 0) * H * H;
        float s = 0.0f;
        for (int j = 0; j < H; ++j) s += W2r[k * H + j] * Wout[j * 2 + o];
        Wc[rel * 128 + k * 2 + o] = s;
        if (rem < 4) {
            int r2 = rem >> 1, o2 = rem & 1;
            const float* b2r = b2 + (r2 ? 2 : 0) * H;
            float sb = 0.0f;
            for (int j = 0; j < H; ++j) sb += b2r[j] * Wout[j * 2 + o2];
            bc[r2 * 2 + o2] = sb;
        }
    }
}

// ---- k2: per-bucket ELL build with LDS cursors ----
__global__ __launch_bounds__(1024)
void radix_build(const unsigned int* __restrict__ bedges1, const int* __restrict__ cur,
                 int* __restrict__ cnt_t2c, int* __restrict__ cols_t2c,
                 int* __restrict__ cnt_t2d, int* __restrict__ cols_t2d) {
    __shared__ int lc[2048];
    int t = threadIdx.x, k = blockIdx.x;     // 0..195
    int rel = k >= 98 ? 1 : 0;
    int shift = rel ? 10 : 11;
    int range = 1 << shift;
    int noff = (rel ? (k - 98) : k) << shift;
    int nN = rel ? ND : NC;
    int* cnt = rel ? cnt_t2d : cnt_t2c;
    int* cols = rel ? cols_t2d : cols_t2c;
    int cap = rel ? CAP_T2D : CAP_T2C;
    int e0 = k * CAP_BK1;
    int e1 = e0 + cur[k];
    for (int i = t; i < range; i += 1024) lc[i] = 0;
    __syncthreads();
    for (int i = e0 + t; i < e1; i += 1024) {
        unsigned int e = bedges1[i];
        int dloc = e >> 19;
        int s = e & 0x7FFFF;
        int l = atomicAdd(&lc[dloc], 1);                       // LDS atomic
        if (l < cap) cols[(size_t)(noff + dloc) * cap + l] = s; // plain store
    }
    __syncthreads();
    for (int i = t; i < range; i += 1024) {
        int gn = noff + i;
        if (gn < nN) cnt[gn] = lc[i];
    }
}

// ---- k3: gather-mean (2 bf16 rows/VMEM) + co-scheduled scatter rel 2,3 ----
__global__ __launch_bounds__(512)
void gather_scatter23(const unsigned int* __restrict__ Xb,
                      const int* __restrict__ cnt_c, const int* __restrict__ cols_c,
                      const int* __restrict__ cnt_d, const int* __restrict__ cols_d,
                      unsigned int* __restrict__ mB,
                      const int* __restrict__ sc2t, const int* __restrict__ dc2t,
                      const int* __restrict__ sd2t, const int* __restrict__ dd2t,
                      int* __restrict__ cur, unsigned int* __restrict__ bedges2) {
    __shared__ unsigned long long le[EPB];
    __shared__ int h[NBK_MAX], pref[NBK_MAX], gbase[NBK_MAX], csr[NBK_MAX];
    __shared__ int wsum[8], woff[8];
    int t = threadIdx.x, b = blockIdx.x;

    if (b < 2 * BPR) {   // scatter rel 2,3 first (starts immediately)
        int rel = 2 + b / BPR;
        int bb = b - (rel - 2) * BPR;
        const int* sp = (rel == 2) ? sc2t : sd2t;
        const int* dp = (rel == 2) ? dc2t : dd2t;
        scatter_body(sp, dp, bb, rel, cur, bedges2, le, h, pref, gbase, csr, wsum, woff);
        return;
    }

    int gb = b - 2 * BPR;
    int lane = t & 63;
    int w = t >> 6;            // 8 waves
    int half = lane >> 5;
    int li = lane & 31;

    int bn, nNodes, cap;
    const int* cnt; const int* cols; unsigned int* mP;
    if (gb < NBGM_C) {
        bn = gb * 64; nNodes = NC; cap = CAP_T2C;
        cnt = cnt_c; cols = cols_c; mP = mB;
    } else {
        bn = (gb - NBGM_C) * 64; nNodes = ND; cap = CAP_T2D;
        cnt = cnt_d; cols = cols_d; mP = mB + (size_t)NC * 32;
    }

    int gnb = bn + w * 8;
    int cval = 0;
    if (lane < 8 && gnb + lane < nNodes) cval = cnt[gnb + lane];

    int cc[8], mm[8], cv[8];
#pragma unroll
    for (int r = 0; r < 8; ++r) {
        cc[r] = __shfl(cval, r);
        mm[r] = cc[r] < cap ? cc[r] : cap;
    }
#pragma unroll
    for (int r = 0; r < 8; ++r) {
        int gn = gnb + r;
        cv[r] = (lane < mm[r] && gn < nNodes) ? cols[(size_t)gn * cap + lane] : 0;
    }

    int maxm = 0;
#pragma unroll
    for (int r = 0; r < 8; ++r) maxm = maxm > mm[r] ? maxm : mm[r];

    float ax[8], ay[8];
#pragma unroll
    for (int r = 0; r < 8; ++r) { ax[r] = 0.0f; ay[r] = 0.0f; }

    for (int j = 0; j < maxm; j += 2) {
#pragma unroll
        for (int r = 0; r < 8; ++r) {
            int sA = __shfl(cv[r], j);
            int sB = __shfl(cv[r], j + 1);
            int src = half ? sB : sA;
            unsigned int v = 0;
            if (j + half < mm[r]) v = Xb[(size_t)src * 32 + li];
            ax[r] += __uint_as_float(v << 16);
            ay[r] += __uint_as_float(v & 0xffff0000u);
        }
    }

#pragma unroll
    for (int r = 0; r < 8; ++r) {
        float fx = ax[r] + __shfl_xor(ax[r], 32);
        float fy = ay[r] + __shfl_xor(ay[r], 32);
        float inv = cc[r] > 0 ? 1.0f / (float)cc[r] : 0.0f;
        ax[r] = fx * inv; ay[r] = fy * inv;
    }
    unsigned int u;
#pragma unroll
    for (int r = 0; r < 8; r += 2) {
        int gn = gnb + r + half;
        float vx = half ? ax[r + 1] : ax[r];
        float vy = half ? ay[r + 1] : ay[r];
        unsigned int pv = BFP(vx) | (BFP(vy) << 16);
        if (gn < nNodes) mP[(size_t)gn * 32 + li] = pv;
    }
}

// ---- k4: xform_tile (4x4 register-tile transform, bf16 means in) ----
__global__ __launch_bounds__(256)
void xform_tile(const unsigned int* __restrict__ mB,
                const int* __restrict__ cnt_c, const int* __restrict__ cnt_d,
                const float* __restrict__ W1, const float* __restrict__ b1,
                const float* __restrict__ Wc, const float* __restrict__ bc,
                float* __restrict__ Pc, float* __restrict__ Pd) {
    __shared__ float Xt[64][68];   // [k][node]
    __shared__ float Wl[64][68];   // [k][col]
    __shared__ float msk[64];
    int t = threadIdx.x;

    int bn, nNodes; const unsigned int* mrow; const int* cnt;
    const float* W1r; const float* b1r; const float* Wcr; const float* bcr;
    float* P;
    if (blockIdx.x < NBX_C) {
        bn = blockIdx.x * 64; nNodes = NC;
        mrow = mB; cnt = cnt_c;
        W1r = W1 + 1 * H * H; b1r = b1 + 1 * H; Wcr = Wc; bcr = bc; P = Pc;
    } else {
        bn = (blockIdx.x - NBX_C) * 64; nNodes = ND;
        mrow = mB + (size_t)NC * 32; cnt = cnt_d;
        W1r = W1 + 3 * H * H; b1r = b1 + 3 * H; Wcr = Wc + 128; bcr = bc + 2; P = Pd;
    }

    {
        int node = t & 63, seg = t >> 6;
        int gn = bn + node;
        uint4 v0 = make_uint4(0, 0, 0, 0), v1 = make_uint4(0, 0, 0, 0);
        if (gn < nNodes) {
            const uint4* rp = (const uint4*)(mrow + (size_t)gn * 32);
            v0 = rp[seg * 2];
            v1 = rp[seg * 2 + 1];
        }
        int k0 = seg * 16;
        Xt[k0 + 0][node] = __uint_as_float(v0.x << 16);
        Xt[k0 + 1][node] = __uint_as_float(v0.x & 0xffff0000u);
        Xt[k0 + 2][node] = __uint_as_float(v0.y << 16);
        Xt[k0 + 3][node] = __uint_as_float(v0.y & 0xffff0000u);
        Xt[k0 + 4][node] = __uint_as_float(v0.z << 16);
        Xt[k0 + 5][node] = __uint_as_float(v0.z & 0xffff0000u);
        Xt[k0 + 6][node] = __uint_as_float(v0.w << 16);
        Xt[k0 + 7][node] = __uint_as_float(v0.w & 0xffff0000u);
        Xt[k0 + 8][node] = __uint_as_float(v1.x << 16);
        Xt[k0 + 9][node] = __uint_as_float(v1.x & 0xffff0000u);
        Xt[k0 + 10][node] = __uint_as_float(v1.y << 16);
        Xt[k0 + 11][node] = __uint_as_float(v1.y & 0xffff0000u);
        Xt[k0 + 12][node] = __uint_as_float(v1.z << 16);
        Xt[k0 + 13][node] = __uint_as_float(v1.z & 0xffff0000u);
        Xt[k0 + 14][node] = __uint_as_float(v1.w << 16);
        Xt[k0 + 15][node] = __uint_as_float(v1.w & 0xffff0000u);
        for (int q = t; q < 1024; q += 256) {
            int kk = q >> 4, s2 = q & 15;
            *(float4*)&Wl[kk][s2 * 4] = *(const float4*)(W1r + kk * H + s2 * 4);
        }
        if (t < 64) msk[t] = (bn + t < nNodes && cnt[bn + t] > 0) ? 1.0f : 0.0f;
    }
    __syncthreads();

    int tj = t & 15;
    int ti = t >> 4;
    float4 b4 = *(const float4*)(b1r + tj * 4);
    float a4[4][4];
#pragma unroll
    for (int r = 0; r < 4; ++r) {
        a4[r][0] = b4.x; a4[r][1] = b4.y; a4[r][2] = b4.z; a4[r][3] = b4.w;
    }
#pragma unroll
    for (int k = 0; k < H; ++k) {
        float4 a = *(const float4*)&Xt[k][ti * 4];
        float4 b = *(const float4*)&Wl[k][tj * 4];
        a4[0][0] = fmaf(a.x, b.x, a4[0][0]); a4[0][1] = fmaf(a.x, b.y, a4[0][1]);
        a4[0][2] = fmaf(a.x, b.z, a4[0][2]); a4[0][3] = fmaf(a.x, b.w, a4[0][3]);
        a4[1][0] = fmaf(a.y, b.x, a4[1][0]); a4[1][1] = fmaf(a.y, b.y, a4[1][1]);
        a4[1][2] = fmaf(a.y, b.z, a4[1][2]); a4[1][3] = fmaf(a.y, b.w, a4[1][3]);
        a4[2][0] = fmaf(a.z, b.x, a4[2][0]); a4[2][1] = fmaf(a.z, b.y, a4[2][1]);
        a4[2][2] = fmaf(a.z, b.z, a4[2][2]); a4[2][3] = fmaf(a.z, b.w, a4[2][3]);
        a4[3][0] = fmaf(a.w, b.x, a4[3][0]); a4[3][1] = fmaf(a.w, b.y, a4[3][1]);
        a4[3][2] = fmaf(a.w, b.z, a4[3][2]); a4[3][3] = fmaf(a.w, b.w, a4[3][3]);
    }

    float4 wca = *(const float4*)(Wcr + tj * 8);
    float4 wcb = *(const float4*)(Wcr + tj * 8 + 4);
    float p0[4], p1[4];
#pragma unroll
    for (int r = 0; r < 4; ++r) {
        float m = msk[ti * 4 + r];
        float h0 = a4[r][0], h1 = a4[r][1], h2 = a4[r][2], h3 = a4[r][3];
        h0 = (h0 > 0.f ? h0 : 0.01f * h0) * m;
        h1 = (h1 > 0.f ? h1 : 0.01f * h1) * m;
        h2 = (h2 > 0.f ? h2 : 0.01f * h2) * m;
        h3 = (h3 > 0.f ? h3 : 0.01f * h3) * m;
        p0[r] = h0 * wca.x + h1 * wca.z + h2 * wcb.x + h3 * wcb.z;
        p1[r] = h0 * wca.y + h1 * wca.w + h2 * wcb.y + h3 * wcb.w;
    }
#pragma unroll
    for (int off = 1; off < 16; off <<= 1) {
#pragma unroll
        for (int r = 0; r < 4; ++r) {
            p0[r] += __shfl_xor(p0[r], off);
            p1[r] += __shfl_xor(p1[r], off);
        }
    }
    if (tj == 0) {
#pragma unroll
        for (int r = 0; r < 4; ++r) {
            int gn = bn + ti * 4 + r;
            if (gn < nNodes) {
                float2 o = make_float2(p0[r] + bcr[0], p1[r] + bcr[1]);
                *(float2*)(P + 2 * (size_t)gn) = o;
            }
        }
    }
}

// ---- pack p into fixed-point uint64 with embedded degree count ----
__device__ __forceinline__ unsigned long long pack_p(const float* __restrict__ P, int s) {
    float2 pv = *(const float2*)(P + 2 * (size_t)s);
    float a = fminf(fmaxf(pv.x, -3.99f), 3.99f);
    float b = fminf(fmaxf(pv.y, -3.99f), 3.99f);
    unsigned int ia = (unsigned int)(__float2int_rn(a * PACK_SCALE) + PACK_BIAS);
    unsigned int ib = (unsigned int)(__float2int_rn(b * PACK_SCALE) + PACK_BIAS);
    return (1ULL << 52) | ((unsigned long long)ia << 26) | (unsigned long long)ib;
}

// ---- k5: layer-2 agg per 1024-node bucket; LDS u64 fixed-point accum ----
__global__ __launch_bounds__(512)
void agg_out(const unsigned int* __restrict__ bedges2, const int* __restrict__ cur,
             const float* __restrict__ Pc, const float* __restrict__ Pd,
             const float* __restrict__ bout, float* __restrict__ out) {
    __shared__ unsigned long long accC[1024], accD[1024];
    int t = threadIdx.x, k = blockIdx.x;
    int noff = k << 10;
    int range = NT - noff; if (range > 1024) range = 1024;
    for (int i = t; i < 1024; i += 512) { accC[i] = 0ULL; accD[i] = 0ULL; }
    __syncthreads();

    int e0 = k * CAP_BK2, e1 = e0 + cur[OFF_C2T + k];
    for (int i = e0 + t; i < e1; i += 512) {
        unsigned int e = bedges2[i];
        int dloc = e >> 19;
        int s = e & 0x7FFFF;
        atomicAdd(&accC[dloc], pack_p(Pc, s));     // LDS u64 atomic
    }
    int f0 = (NBK2 + k) * CAP_BK2, f1 = f0 + cur[OFF_D2T + k];
    for (int i = f0 + t; i < f1; i += 512) {
        unsigned int e = bedges2[i];
        int dloc = e >> 19;
        int s = e & 0x7FFFF;
        atomicAdd(&accD[dloc], pack_p(Pd, s));
    }
    __syncthreads();

    float bo0 = bout[0], bo1 = bout[1];
    const float inv_s = 1.0f / PACK_SCALE;
    for (int i = t; i < range; i += 512) {
        unsigned long long xc = accC[i];
        unsigned long long xd = accD[i];
        int dc = (int)(xc >> 52);
        int dd = (int)(xd >> 52);
        float ic = dc > 0 ? 1.0f / (float)dc : 0.0f;
        float id = dd > 0 ? 1.0f / (float)dd : 0.0f;
        float c0 = (float)((long long)((xc >> 26) & FIELD_MASK) - (long long)dc * PACK_BIAS);
        float c1 = (float)((long long)(xc & FIELD_MASK) - (long long)dc * PACK_BIAS);
        float d0 = (float)((long long)((xd >> 26) & FIELD_MASK) - (long long)dd * PACK_BIAS);
        float d1 = (float)((long long)(xd & FIELD_MASK) - (long long)dd * PACK_BIAS);
        float2 o;
        o.x = bo0 + (c0 * ic + d0 * id) * inv_s;
        o.y = bo1 + (c1 * ic + d1 * id) * inv_s;
        *(float2*)(out + 2 * (size_t)(noff + i)) = o;
    }
}

extern "C" void kernel_launch(void* const* d_in, const int* in_sizes, int n_in,
                              void* d_out, int out_size, void* d_ws, size_t ws_size,
                              hipStream_t stream) {
    const float* features = (const float*)d_in[0];
    const float* W1 = (const float*)d_in[3];
    const float* b1 = (const float*)d_in[4];
    const float* W2 = (const float*)d_in[5];
    const float* b2 = (const float*)d_in[6];
    const float* W_out = (const float*)d_in[7];
    const float* b_out = (const float*)d_in[8];
    const int* src_c2t = (const int*)d_in[9];
    const int* dst_c2t = (const int*)d_in[10];
    const int* src_t2c = (const int*)d_in[11];
    const int* dst_t2c = (const int*)d_in[12];
    const int* src_d2t = (const int*)d_in[13];
    const int* dst_d2t = (const int*)d_in[14];
    const int* src_t2d = (const int*)d_in[15];
    const int* dst_t2d = (const int*)d_in[16];
    float* out = (float*)d_out;

    // ---- workspace carve ----
    char* w = (char*)d_ws;
    int* cur = (int*)w;                           w += 2048 * 4;   // ZERO region (8 KB)
    size_t zero_bytes = 2048 * 4;
    int* cnt_t2c = (int*)w;                       w += (size_t)NC * 4;
    int* cnt_t2d = (int*)w;                       w += (size_t)ND * 4;
    int* cols_t2c = (int*)w;                      w += (size_t)NC * CAP_T2C * 4;
    int* cols_t2d = (int*)w;                      w += (size_t)ND * CAP_T2D * 4;
    float* p_c = (float*)w;                       w += (size_t)NC * 2 * 4;
    float* p_d = (float*)w;                       w += (size_t)ND * 2 * 4;
    float* Wc = (float*)w;                        w += 256 * 4;
    float* bc = (float*)w;                        w += 16;
    unsigned int* bedges1 = (unsigned int*)w;     w += (size_t)196 * CAP_BK1 * 4;        // 9.2 MB
    unsigned int* bedges2 = (unsigned int*)w;     w += (size_t)(2 * NBK2) * CAP_BK2 * 4; // 10.5 MB
    unsigned int* Xb = (unsigned int*)w;          w += (size_t)NT * H * 2;               // 64 MB
    unsigned int* mB = (unsigned int*)w;          w += ((size_t)(NC + ND) + 64) * 32 * 4; // 38.4 MB

    hipMemsetAsync(d_ws, 0, zero_bytes, stream);

    // k1: scatter rel 0,1 + compress + prep_fold
    scatter01_compress<<<2 * BPR + CB512 + 1, 512, 0, stream>>>(
        src_t2c, dst_t2c, src_t2d, dst_t2d,
        cur, bedges1, features, Xb, W2, b2, W_out, Wc, bc);

    // k2: ELL build for layer-1
    radix_build<<<196, 1024, 0, stream>>>(bedges1, cur,
                                          cnt_t2c, cols_t2c, cnt_t2d, cols_t2d);

    // k3: gather-mean co-scheduled with scatter rel 2,3
    gather_scatter23<<<2 * BPR + NBGM_C + NBGM_D, 512, 0, stream>>>(
        Xb, cnt_t2c, cols_t2c, cnt_t2d, cols_t2d, mB,
        src_c2t, dst_c2t, src_d2t, dst_d2t, cur, bedges2);

    // k4: transform + fold
    xform_tile<<<NBX_C + NBX_D, 256, 0, stream>>>(
        mB, cnt_t2c, cnt_t2d, W1, b1, Wc, bc, p_c, p_d);

    // k5: layer-2 aggregation straight into out
    agg_out<<<NBK2, 512, 0, stream>>>(bedges2, cur, p_c, p_d, b_out, out);
}